// Round 2
// baseline (166.989 us; speedup 1.0000x reference)
//
#include <hip/hip_runtime.h>

// MFVIConstituency: q[b,i,j] = s_con[b,i,j] + sum_k sig(q)[b,j,k] * s_bin[b,i,j,k] * (i!=k)*(j!=k)*mask[b,i,j]
// 3 fixed-point iterations, output sigmoid(q). Memory-bound on s_bin (226 MB per pass).
// mask arrives as int32 (harness widens bool -> int).

#define S_DIM 192
#define SS (S_DIM * S_DIM)
#define B_DIM 8
#define NROWS (B_DIM * SS)   // 294912 = number of (b,i,j) outputs

__device__ __forceinline__ float sigmoidf(float x) {
    return 1.0f / (1.0f + __expf(-x));
}

// sig0 = sigmoid(s_con), elementwise
__global__ __launch_bounds__(256) void sig_init_kernel(const float* __restrict__ s_con,
                                                       float* __restrict__ sig) {
    int idx = blockIdx.x * 256 + threadIdx.x;
    if (idx < NROWS) sig[idx] = sigmoidf(s_con[idx]);
}

// One wave (64 lanes) per output row (b,i,j). Lanes 0..47 each load one float4
// of s_bin[b,i,j,:] (768 B contiguous) and the matching float4 of sig_in[b,j,:].
// Mask (k!=i && k!=j) applied as predicate; wave shuffle-reduce; epilogue fuses
// s_con add, row mask, and sigmoid. 4 waves (4 rows) per 256-thread block.
__global__ __launch_bounds__(256) void fvi_iter_kernel(const float* __restrict__ s_con,
                                                       const float* __restrict__ s_bin,
                                                       const int* __restrict__ mask,
                                                       const float* __restrict__ sig_in,
                                                       float* __restrict__ sig_out) {
    const int wave = threadIdx.x >> 6;
    const int lane = threadIdx.x & 63;
    const int row  = (blockIdx.x << 2) + wave;   // grid sized exactly: row < NROWS

    const int b   = row / SS;
    const int rem = row - b * SS;
    const int i   = rem / S_DIM;
    const int j   = rem - i * S_DIM;

    const float4* __restrict__ srow   = reinterpret_cast<const float4*>(s_bin + (size_t)row * S_DIM);
    const float4* __restrict__ sigrow = reinterpret_cast<const float4*>(sig_in + (size_t)(b * SS + j * S_DIM));

    float dot = 0.0f;
    if (lane < (S_DIM / 4)) {          // 48 float4 per row
        float4 sv = srow[lane];
        float4 gv = sigrow[lane];
        const int k0 = lane << 2;
        float p0 = (k0 + 0 != i && k0 + 0 != j) ? sv.x * gv.x : 0.0f;
        float p1 = (k0 + 1 != i && k0 + 1 != j) ? sv.y * gv.y : 0.0f;
        float p2 = (k0 + 2 != i && k0 + 2 != j) ? sv.z * gv.z : 0.0f;
        float p3 = (k0 + 3 != i && k0 + 3 != j) ? sv.w * gv.w : 0.0f;
        dot = (p0 + p1) + (p2 + p3);
    }

    #pragma unroll
    for (int off = 32; off > 0; off >>= 1)
        dot += __shfl_xor(dot, off, 64);

    if (lane == 0) {
        float q = s_con[row] + (mask[row] ? dot : 0.0f);
        sig_out[row] = sigmoidf(q);
    }
}

extern "C" void kernel_launch(void* const* d_in, const int* in_sizes, int n_in,
                              void* d_out, int out_size, void* d_ws, size_t ws_size,
                              hipStream_t stream) {
    const float* s_con = (const float*)d_in[0];
    const float* s_bin = (const float*)d_in[1];
    const int*   mask  = (const int*)d_in[2];   // harness widens bool -> int32
    float* out  = (float*)d_out;
    float* sigW = (float*)d_ws;                  // 1.18 MB scratch

    // ping-pong: ws -> out -> ws -> out (final iteration lands in d_out)
    sig_init_kernel<<<(NROWS + 255) / 256, 256, 0, stream>>>(s_con, sigW);

    const dim3 grid(NROWS / 4);   // 4 rows (waves) per block
    fvi_iter_kernel<<<grid, 256, 0, stream>>>(s_con, s_bin, mask, sigW, out);
    fvi_iter_kernel<<<grid, 256, 0, stream>>>(s_con, s_bin, mask, out, sigW);
    fvi_iter_kernel<<<grid, 256, 0, stream>>>(s_con, s_bin, mask, sigW, out);
}

// Round 4
// 108.127 us; speedup vs baseline: 1.5444x; 1.5444x over previous
//
#include <hip/hip_runtime.h>

// MFVIConstituency: q[b,i,j] = s_con[b,i,j] + sum_k sig(q)[b,j,k] * s_bin[b,i,j,k] * (i!=k)*(j!=k)*mask[b,i,j]
// MAX_ITER=3 fixed-point iterations, output sigmoid(q). Memory-bound on s_bin (226 MB/pass).
// mask arrives as int32 (harness widens bool -> int).
//
// Layout: one wave = 4 consecutive (b,i,j) rows; 16 lanes per row; 3 float4 per
// lane -> all 64 lanes stream, 4x256B fully-used segments per load instruction.
// Iteration 1 reads s_con directly and applies sigmoid on the fly (APPLY_SIG),
// so exactly 3 dispatches total: s_con -> wsA -> wsB -> d_out.

#define S_DIM 192
#define SS (S_DIM * S_DIM)
#define B_DIM 8
#define NROWS (B_DIM * SS)   // 294912 outputs

__device__ __forceinline__ float sigmoidf(float x) {
    return 1.0f / (1.0f + __expf(-x));
}

template <bool APPLY_SIG>
__global__ __launch_bounds__(256) void fvi_iter_kernel(const float* __restrict__ s_con,
                                                       const float* __restrict__ s_bin,
                                                       const int* __restrict__ mask,
                                                       const float* __restrict__ sig_in,
                                                       float* __restrict__ sig_out) {
    const int wave = threadIdx.x >> 6;
    const int lane = threadIdx.x & 63;
    const int grp  = lane >> 4;                      // which of the 4 rows
    const int sub  = lane & 15;                      // lane within row group
    const int row0 = (blockIdx.x * 4 + wave) * 4;    // 16 rows/block, 4/wave
    const int row  = row0 + grp;

    const int b   = row / SS;                        // 4-row group never crosses b or i
    const int rem = row - b * SS;
    const int i   = rem / S_DIM;
    const int j   = rem - i * S_DIM;

    const float4* __restrict__ srow = reinterpret_cast<const float4*>(s_bin + (size_t)row * S_DIM);
    const float4* __restrict__ grow = reinterpret_cast<const float4*>(sig_in + (size_t)(b * SS + j * S_DIM));

    float dot = 0.0f;
    #pragma unroll
    for (int c = 0; c < 3; ++c) {
        const int f4 = sub + (c << 4);               // 0..47
        float4 sv = srow[f4];
        float4 gv = grow[f4];
        if (APPLY_SIG) {                             // iter 1: sig_in is s_con
            gv.x = sigmoidf(gv.x);
            gv.y = sigmoidf(gv.y);
            gv.z = sigmoidf(gv.z);
            gv.w = sigmoidf(gv.w);
        }
        const int k0 = f4 << 2;
        dot += (k0 + 0 != i && k0 + 0 != j) ? sv.x * gv.x : 0.0f;
        dot += (k0 + 1 != i && k0 + 1 != j) ? sv.y * gv.y : 0.0f;
        dot += (k0 + 2 != i && k0 + 2 != j) ? sv.z * gv.z : 0.0f;
        dot += (k0 + 3 != i && k0 + 3 != j) ? sv.w * gv.w : 0.0f;
    }

    // reduce across the 16 lanes owning this row
    dot += __shfl_xor(dot, 1, 64);
    dot += __shfl_xor(dot, 2, 64);
    dot += __shfl_xor(dot, 4, 64);
    dot += __shfl_xor(dot, 8, 64);

    if (sub == 0) {
        float q = s_con[row] + (mask[row] ? dot : 0.0f);
        sig_out[row] = sigmoidf(q);
    }
}

extern "C" void kernel_launch(void* const* d_in, const int* in_sizes, int n_in,
                              void* d_out, int out_size, void* d_ws, size_t ws_size,
                              hipStream_t stream) {
    const float* s_con = (const float*)d_in[0];
    const float* s_bin = (const float*)d_in[1];
    const int*   mask  = (const int*)d_in[2];   // harness widens bool -> int32
    float* out  = (float*)d_out;
    float* sigA = (float*)d_ws;                 // 2 x 1.18 MB scratch
    float* sigB = sigA + NROWS;

    const dim3 grid(NROWS / 16);                // 16 rows per 256-thread block

    // exactly MAX_ITER=3 iterations; iter 1 applies sigmoid to s_con on the fly
    fvi_iter_kernel<true ><<<grid, 256, 0, stream>>>(s_con, s_bin, mask, s_con, sigA);
    fvi_iter_kernel<false><<<grid, 256, 0, stream>>>(s_con, s_bin, mask, sigA, sigB);
    fvi_iter_kernel<false><<<grid, 256, 0, stream>>>(s_con, s_bin, mask, sigB, out);
}

// Round 6
// 104.330 us; speedup vs baseline: 1.6006x; 1.0364x over previous
//
#include <hip/hip_runtime.h>

// MFVIConstituency: q[b,i,j] = s_con[b,i,j] + sum_k sig(q)[b,j,k] * s_bin[b,i,j,k] * (i!=k)*(j!=k)*mask[b,i,j]
// MAX_ITER=3, output sigmoid(q). Memory-bound.
//
// Strategy: iter 1 reads fp32 s_bin once (non-temporal) and emits a MASKED
// fp16 copy (113 MB, fits L3 with 2x headroom). Iters 2-3 read the fp16 copy.
// Traffic 679 -> ~566 MB, with iters 2-3 likely served from Infinity Cache.
//
// Layout: one wave = 4 consecutive (b,i,j) rows; 16 lanes per row; 3 chunks of
// 4 elements per lane -> all 64 lanes stream, fully-used segments.

#define S_DIM 192
#define SS (S_DIM * S_DIM)
#define B_DIM 8
#define NROWS (B_DIM * SS)   // 294912 outputs

typedef float floatx4 __attribute__((ext_vector_type(4)));   // native vec for NT builtins
struct alignas(8) half4 { _Float16 x, y, z, w; };

__device__ __forceinline__ float sigmoidf(float x) {
    return 1.0f / (1.0f + __expf(-x));
}

// iteration 1: fp32 s_bin (streaming, NT), fold k-mask, emit fp16 copy + sig(q1)
__global__ __launch_bounds__(256) void fvi_first_kernel(const float* __restrict__ s_con,
                                                        const float* __restrict__ s_bin,
                                                        const int* __restrict__ mask,
                                                        half4* __restrict__ sbh,
                                                        float* __restrict__ sig_out) {
    const int wave = threadIdx.x >> 6;
    const int lane = threadIdx.x & 63;
    const int grp  = lane >> 4;
    const int sub  = lane & 15;
    const int row  = (blockIdx.x * 4 + wave) * 4 + grp;

    const int b   = row / SS;
    const int rem = row - b * SS;
    const int i   = rem / S_DIM;
    const int j   = rem - i * S_DIM;

    const floatx4* __restrict__ srow = reinterpret_cast<const floatx4*>(s_bin + (size_t)row * S_DIM);
    const float4*  __restrict__ grow = reinterpret_cast<const float4*>(s_con + (size_t)(b * SS + j * S_DIM));
    half4* __restrict__ hrow = sbh + (size_t)row * (S_DIM / 4);

    float dot = 0.0f;
    #pragma unroll
    for (int c = 0; c < 3; ++c) {
        const int f4 = sub + (c << 4);               // 0..47
        floatx4 sv = __builtin_nontemporal_load(srow + f4);
        float4  gv = grow[f4];
        const int k0 = f4 << 2;
        const float m0 = (k0 + 0 != i && k0 + 0 != j) ? sv.x : 0.0f;
        const float m1 = (k0 + 1 != i && k0 + 1 != j) ? sv.y : 0.0f;
        const float m2 = (k0 + 2 != i && k0 + 2 != j) ? sv.z : 0.0f;
        const float m3 = (k0 + 3 != i && k0 + 3 != j) ? sv.w : 0.0f;
        dot += m0 * sigmoidf(gv.x) + m1 * sigmoidf(gv.y)
             + m2 * sigmoidf(gv.z) + m3 * sigmoidf(gv.w);
        half4 hv;
        hv.x = (_Float16)m0; hv.y = (_Float16)m1;
        hv.z = (_Float16)m2; hv.w = (_Float16)m3;
        hrow[f4] = hv;
    }

    dot += __shfl_xor(dot, 1, 64);
    dot += __shfl_xor(dot, 2, 64);
    dot += __shfl_xor(dot, 4, 64);
    dot += __shfl_xor(dot, 8, 64);

    if (sub == 0) {
        float q = s_con[row] + (mask[row] ? dot : 0.0f);
        sig_out[row] = sigmoidf(q);
    }
}

// iterations 2..3: read masked fp16 copy (L3-resident), no k-mask needed
__global__ __launch_bounds__(256) void fvi_iter_kernel(const float* __restrict__ s_con,
                                                       const half4* __restrict__ sbh,
                                                       const int* __restrict__ mask,
                                                       const float* __restrict__ sig_in,
                                                       float* __restrict__ sig_out) {
    const int wave = threadIdx.x >> 6;
    const int lane = threadIdx.x & 63;
    const int grp  = lane >> 4;
    const int sub  = lane & 15;
    const int row  = (blockIdx.x * 4 + wave) * 4 + grp;

    const int b   = row / SS;
    const int rem = row - b * SS;
    const int j   = rem - (rem / S_DIM) * S_DIM;

    const half4*  __restrict__ hrow = sbh + (size_t)row * (S_DIM / 4);
    const float4* __restrict__ grow = reinterpret_cast<const float4*>(sig_in + (size_t)(b * SS + j * S_DIM));

    float dot = 0.0f;
    #pragma unroll
    for (int c = 0; c < 3; ++c) {
        const int f4 = sub + (c << 4);
        half4  hv = hrow[f4];
        float4 gv = grow[f4];
        dot += (float)hv.x * gv.x + (float)hv.y * gv.y
             + (float)hv.z * gv.z + (float)hv.w * gv.w;
    }

    dot += __shfl_xor(dot, 1, 64);
    dot += __shfl_xor(dot, 2, 64);
    dot += __shfl_xor(dot, 4, 64);
    dot += __shfl_xor(dot, 8, 64);

    if (sub == 0) {
        float q = s_con[row] + (mask[row] ? dot : 0.0f);
        sig_out[row] = sigmoidf(q);
    }
}

extern "C" void kernel_launch(void* const* d_in, const int* in_sizes, int n_in,
                              void* d_out, int out_size, void* d_ws, size_t ws_size,
                              hipStream_t stream) {
    const float* s_con = (const float*)d_in[0];
    const float* s_bin = (const float*)d_in[1];
    const int*   mask  = (const int*)d_in[2];   // harness widens bool -> int32
    float* out  = (float*)d_out;
    float* sigA = (float*)d_ws;
    float* sigB = sigA + NROWS;
    half4* sbh  = reinterpret_cast<half4*>(sigB + NROWS);  // 113 MB fp16 masked copy

    const dim3 grid(NROWS / 16);                // 16 rows per 256-thread block

    fvi_first_kernel<<<grid, 256, 0, stream>>>(s_con, s_bin, mask, sbh, sigA);
    fvi_iter_kernel <<<grid, 256, 0, stream>>>(s_con, sbh, mask, sigA, sigB);
    fvi_iter_kernel <<<grid, 256, 0, stream>>>(s_con, sbh, mask, sigB, out);
}